// Round 15
// baseline (101.119 us; speedup 1.0000x reference)
//
#include <hip/hip_runtime.h>

#define NFREQ   257
#define NFRAMES 3751
#define NS      480000
#define HOP     128
#define WIN     512

#define NB      32
#define BN      256                 // frames per block
#define NFT     15                  // 15*256 = 3840 frames
#define STEPS   32                  // 2 fp * 16 k32
#define XWPITCH 272                 // 128 samples (256B) + 16B pad
#define XW_B    70448               // 259 rows * 272
#define ASTEP   16384               // one A step image: [2pl][128r][64B]
#define WNYQ_B  1024
#define XGROUPS 4144                // 33152 samples / 8

typedef __attribute__((ext_vector_type(8))) short short8;
typedef __attribute__((ext_vector_type(4))) float f32x4;

__device__ __forceinline__ short f2bf(float f) {
    __bf16 b = (__bf16)f;
    return __builtin_bit_cast(short, b);
}
__device__ __forceinline__ float bf2f(short s) {
    unsigned int u = ((unsigned int)(unsigned short)s) << 16;
    return __builtin_bit_cast(float, u);
}
__device__ __forceinline__ void gload_lds16(const void* g, void* l) {
    __builtin_amdgcn_global_load_lds(
        (const __attribute__((address_space(1))) void*)g,
        (__attribute__((address_space(3))) void*)l, 16, 0, 0);
}

// ---- prep: bake 32-step A stream, image [2pl][128row][4slot x 16B] per step.
// content at (step, pl, row, slot): kg = slot ^ ((row>>2)&3);
// basis[pl, (step>>4)*128 + row, (step&15)*32 + kg*8 .. +8]
__global__ __launch_bounds__(256)
void prep_basis5(const float* __restrict__ basis,
                 short* __restrict__ abL, short* __restrict__ wnyqG) {
    int g = blockIdx.x * 256 + threadIdx.x;
    if (g < 32768) {
        int ob   = g * 16;
        int step = ob >> 14;                 // 0..31
        int rem  = ob & 16383;
        int pl   = rem >> 13;
        int row  = (rem >> 6) & 127;
        int slot = (rem >> 4) & 3;
        int kg   = slot ^ ((row >> 2) & 3);
        int fr   = (step >> 4) * 128 + row;            // 0..255 < 257
        int k0   = (step & 15) * 32 + kg * 8;
        const float4* p = reinterpret_cast<const float4*>(
            basis + ((size_t)(pl * NFREQ + fr)) * WIN + k0);
        float4 a0 = p[0], a1 = p[1];
        short8 v;
        v[0]=f2bf(a0.x); v[1]=f2bf(a0.y); v[2]=f2bf(a0.z); v[3]=f2bf(a0.w);
        v[4]=f2bf(a1.x); v[5]=f2bf(a1.y); v[6]=f2bf(a1.z); v[7]=f2bf(a1.w);
        *reinterpret_cast<short8*>(reinterpret_cast<char*>(abL) + ob) = v;
    } else if (g < 32832) {                  // nyq row: real plane row 256
        int j = g - 32768;
        const float4* p = reinterpret_cast<const float4*>(basis + (size_t)256 * WIN + j * 8);
        float4 a0 = p[0], a1 = p[1];
        short8 v;
        v[0]=f2bf(a0.x); v[1]=f2bf(a0.y); v[2]=f2bf(a0.z); v[3]=f2bf(a0.w);
        v[4]=f2bf(a1.x); v[5]=f2bf(a1.y); v[6]=f2bf(a1.z); v[7]=f2bf(a1.w);
        *reinterpret_cast<short8*>(wnyqG + j * 8) = v;
    }
}

// ---- main: 512 thr, 8 waves (2 freq x 4 frame), 128f x 256t; counted-vmcnt
// triple-buffered A pipeline (depth 2), raw barriers, setprio MFMA cluster ----
__global__ __launch_bounds__(512, 2)
void stft_mfma_kernel(const float* __restrict__ x,
                      const short* __restrict__ abL,
                      const short* __restrict__ wnyqG,
                      float* __restrict__ out)
{
    __shared__ __align__(16) char smem[XW_B + 3 * ASTEP + WNYQ_B];  // 120624 B
    char* const xw   = smem;
    char* const aBuf = smem + XW_B;
    char* const wnyq = smem + XW_B + 3 * ASTEP;

    const int tid  = threadIdx.x;
    const int wave = tid >> 6;
    const int lane = tid & 63;
    const int wr   = wave >> 2;          // 0..1 : freq half (64 rows)
    const int wc   = wave & 3;           // 0..3 : frame quarter (64 frames)
    const int lgrp = lane >> 4;
    const int l15  = lane & 15;

    // bijective XCD chunk swizzle: 480 = 8 * 60
    const int logical = (blockIdx.x & 7) * 60 + (blockIdx.x >> 3);
    const int ft = logical % NFT;
    const int b  = logical / NFT;
    const int t0 = ft * BN;

    const char* abLc = (const char*)abL;

    // ---- prologue: fp32 x window -> bf16 LDS (padded rows, reflect edges) ----
    {
        const float* __restrict__ xb = x + (size_t)b * NS;
        const int sbase = t0 * 128 - 256;
        #pragma unroll
        for (int i = 0; i < 9; ++i) {
            int g = tid + i * 512;
            if (g < XGROUPS) {
                int ix = sbase + g * 8;
                short8 v;
                if (ix >= 0 && ix + 8 <= NS) {
                    const float4* p = reinterpret_cast<const float4*>(xb + ix);
                    float4 a0 = p[0], a1 = p[1];
                    v[0]=f2bf(a0.x); v[1]=f2bf(a0.y); v[2]=f2bf(a0.z); v[3]=f2bf(a0.w);
                    v[4]=f2bf(a1.x); v[5]=f2bf(a1.y); v[6]=f2bf(a1.z); v[7]=f2bf(a1.w);
                } else {
                    #pragma unroll
                    for (int q = 0; q < 8; ++q) {
                        int idx = ix + q;
                        if (idx < 0) idx = -idx;
                        if (idx >= NS + 256) { v[q] = 0; continue; }
                        if (idx >= NS) idx = 2 * NS - 2 - idx;
                        v[q] = f2bf(xb[idx]);
                    }
                }
                *reinterpret_cast<short8*>(xw + (g >> 4) * XWPITCH + (g & 15) * 16) = v;
            }
        }
    }
    // nyq weights + stage(0), stage(1) issues; then full drain once
    if (wave == 0)
        gload_lds16((const char*)wnyqG + lane * 16, wnyq);
    #pragma unroll
    for (int st = 0; st < 2; ++st) {
        const char* sb = abLc + (size_t)st * ASTEP;
        char* dst = aBuf + st * ASTEP;
        int c = wave * 2;
        gload_lds16(sb + c * 1024 + lane * 16, dst + c * 1024);
        gload_lds16(sb + (c + 1) * 1024 + lane * 16, dst + (c + 1) * 1024);
    }
    __syncthreads();    // full drain (prologue only)

    f32x4 accR[4][4], accI[4][4];
    #pragma unroll
    for (int m = 0; m < 4; ++m)
        #pragma unroll
        for (int n = 0; n < 4; ++n) {
            accR[m][n] = f32x4{0.f,0.f,0.f,0.f};
            accI[m][n] = f32x4{0.f,0.f,0.f,0.f};
        }

    const int aSlot = (lgrp ^ (l15 >> 2)) << 4;   // A slot swizzle (per-lane const)
    const int aRow0 = wr * 64 + l15;

    #pragma unroll 1
    for (int s = 0; s < STEPS; ++s) {
        // counted wait: stage(s) landed; stage(s+1)'s 2 loads may stay in flight.
        // fp boundary (s=0,16): epilogue stores pollute the FIFO -> full drain.
        if ((s & 15) == 0) {
            asm volatile("s_waitcnt vmcnt(0)" ::: "memory");
        } else {
            asm volatile("s_waitcnt vmcnt(2)" ::: "memory");
        }
        asm volatile("s_waitcnt lgkmcnt(0)" ::: "memory");   // reads of s-1 consumed (cheap)
        __builtin_amdgcn_sched_barrier(0);
        __builtin_amdgcn_s_barrier();                        // raw barrier, no drain
        __builtin_amdgcn_sched_barrier(0);

        // ---- issue stage(s+2) into buffer (s+2)%3 (2-barrier write separation) ----
        if (s + 2 < STEPS) {
            const char* sb = abLc + (size_t)(s + 2) * ASTEP;
            char* dst = aBuf + ((s + 2) % 3) * ASTEP;
            int c = wave * 2;
            gload_lds16(sb + c * 1024 + lane * 16, dst + c * 1024);
            gload_lds16(sb + (c + 1) * 1024 + lane * 16, dst + (c + 1) * 1024);
        }
        __builtin_amdgcn_sched_barrier(0);

        // ---- compute(s) from buffer s%3 ----
        const char* aCur = aBuf + (s % 3) * ASTEP;
        const int ks32 = s & 15;
        short8 aRv[4], aIv[4], xv[4];
        #pragma unroll
        for (int m = 0; m < 4; ++m) {
            int off = (aRow0 + m * 16) * 64 + aSlot;
            aRv[m] = *reinterpret_cast<const short8*>(aCur + off);
            aIv[m] = *reinterpret_cast<const short8*>(aCur + 8192 + off);
        }
        {
            int flat0 = (wc * 64 + l15) * 256 + ks32 * 64 + lgrp * 16;
            const char* xwl = xw + flat0 + ((flat0 >> 8) << 4);
            #pragma unroll
            for (int nt = 0; nt < 4; ++nt)
                xv[nt] = *reinterpret_cast<const short8*>(xwl + nt * (16 * XWPITCH));
        }
        __builtin_amdgcn_s_setprio(1);
        #pragma unroll
        for (int m = 0; m < 4; ++m)
            #pragma unroll
            for (int nt = 0; nt < 4; ++nt) {
                accR[m][nt] = __builtin_amdgcn_mfma_f32_16x16x32_bf16(aRv[m], xv[nt], accR[m][nt], 0, 0, 0);
                accI[m][nt] = __builtin_amdgcn_mfma_f32_16x16x32_bf16(aIv[m], xv[nt], accI[m][nt], 0, 0, 0);
            }
        __builtin_amdgcn_s_setprio(0);

        // ---- per-fp epilogue ----
        if ((s & 15) == 15) {
            const int fp = s >> 4;
            float* ob = out + (size_t)b * NFREQ * NFRAMES;
            const int fb = fp * 128 + wr * 64 + lgrp * 4;
            const int tb = t0 + wc * 64 + l15;
            #pragma unroll
            for (int m = 0; m < 4; ++m)
                #pragma unroll
                for (int nt = 0; nt < 4; ++nt) {
                    int t = tb + nt * 16;
                    if (t < NFRAMES) {
                        #pragma unroll
                        for (int r = 0; r < 4; ++r) {
                            int f = fb + m * 16 + r;
                            float vr = accR[m][nt][r], vi = accI[m][nt][r];
                            ob[(size_t)f * NFRAMES + t] = sqrtf(vr * vr + vi * vi);
                        }
                    }
                    accR[m][nt] = f32x4{0.f,0.f,0.f,0.f};
                    accI[m][nt] = f32x4{0.f,0.f,0.f,0.f};
                }
        }
    }

    // ---- Nyquist tail: f=256, |dot(x_frame, w)|; x & w in LDS ----
    {
        const int fl = wave * 32 + (lane & 31);       // local frame 0..255
        const int h  = lane >> 5;                     // window half
        const int xbase = (fl + 2 * h) * XWPITCH;
        const int wbase = h * 512;
        float acc = 0.f;
        #pragma unroll
        for (int j = 0; j < 32; ++j) {
            short8 xv8 = *reinterpret_cast<const short8*>(
                xw + xbase + (j >> 4) * XWPITCH + (j & 15) * 16);
            short8 wv8 = *reinterpret_cast<const short8*>(wnyq + wbase + j * 16);
            #pragma unroll
            for (int q = 0; q < 8; ++q)
                acc = fmaf(bf2f(xv8[q]), bf2f(wv8[q]), acc);
        }
        acc += __shfl_xor(acc, 32);
        int t = t0 + fl;
        if (h == 0 && t < NFRAMES)
            out[((size_t)b * NFREQ + 256) * NFRAMES + t] = fabsf(acc);
    }
}

extern "C" void kernel_launch(void* const* d_in, const int* in_sizes, int n_in,
                              void* d_out, int out_size, void* d_ws, size_t ws_size,
                              hipStream_t stream) {
    const float* x     = (const float*)d_in[0];
    const float* basis = (const float*)d_in[1];
    float* out = (float*)d_out;

    short* abL   = (short*)d_ws;                      // 32 steps x 16KB = 512KB
    short* wnyqG = abL + 262144;                      // 512 bf16

    prep_basis5<<<dim3(129), 256, 0, stream>>>(basis, abL, wnyqG);
    stft_mfma_kernel<<<dim3(NFT * NB), 512, 0, stream>>>(x, abL, wnyqG, out);  // 480 blocks
}

// Round 16
// 96.545 us; speedup vs baseline: 1.0474x; 1.0474x over previous
//
#include <hip/hip_runtime.h>

#define NFREQ   257
#define NFRAMES 3751
#define NS      480000
#define HOP     128
#define WIN     512

#define NB      32
#define BN      256                 // frames per block
#define NFT     15                  // 15*256 = 3840 frames
#define STEPS   32                  // 2 fp * 16 k32
#define XWPITCH 272                 // 128 samples (256B) + 16B pad
#define XW_B    70448               // 259 rows * 272
#define ASTEP   16384               // one A step image: [2pl][4 kslot][128 row x 16B]
#define WNYQ_B  1024
#define XGROUPS 4144                // 33152 samples / 8

typedef __attribute__((ext_vector_type(8))) short short8;
typedef __attribute__((ext_vector_type(4))) float f32x4;

__device__ __forceinline__ short f2bf(float f) {
    __bf16 b = (__bf16)f;
    return __builtin_bit_cast(short, b);
}
__device__ __forceinline__ float bf2f(short s) {
    unsigned int u = ((unsigned int)(unsigned short)s) << 16;
    return __builtin_bit_cast(float, u);
}
__device__ __forceinline__ void gload_lds16(const void* g, void* l) {
    __builtin_amdgcn_global_load_lds(
        (const __attribute__((address_space(1))) void*)g,
        (__attribute__((address_space(3))) void*)l, 16, 0, 0);
}

// ---- prep: bake 32-step A stream, image [pl][kslot][row x 16B] per step.
// byte ob in step image: pl=ob>>13, kslot=(ob>>11)&3, row=(ob>>4)&127, j=ob&15.
// content: basis[pl, (step>>4)*128+row, (step&15)*32 + kslot*8 .. +8]  (bf16)
// A-read in kernel: 16 lanes -> 16 consecutive 16B slots = 256B contiguous,
// banks 0..31 exactly once -> ZERO conflicts (r15's layout was 8-way).
__global__ __launch_bounds__(256)
void prep_basis6(const float* __restrict__ basis,
                 short* __restrict__ abL, short* __restrict__ wnyqG) {
    int g = blockIdx.x * 256 + threadIdx.x;
    if (g < 32768) {
        int ob    = g * 16;
        int step  = ob >> 14;                 // 0..31
        int rem   = ob & 16383;
        int pl    = rem >> 13;
        int kslot = (rem >> 11) & 3;
        int row   = (rem >> 4) & 127;
        int fr    = (step >> 4) * 128 + row;            // 0..255 < 257
        int k0    = (step & 15) * 32 + kslot * 8;
        const float4* p = reinterpret_cast<const float4*>(
            basis + ((size_t)(pl * NFREQ + fr)) * WIN + k0);
        float4 a0 = p[0], a1 = p[1];
        short8 v;
        v[0]=f2bf(a0.x); v[1]=f2bf(a0.y); v[2]=f2bf(a0.z); v[3]=f2bf(a0.w);
        v[4]=f2bf(a1.x); v[5]=f2bf(a1.y); v[6]=f2bf(a1.z); v[7]=f2bf(a1.w);
        *reinterpret_cast<short8*>(reinterpret_cast<char*>(abL) + ob) = v;
    } else if (g < 32832) {                  // nyq row: real plane row 256
        int j = g - 32768;
        const float4* p = reinterpret_cast<const float4*>(basis + (size_t)256 * WIN + j * 8);
        float4 a0 = p[0], a1 = p[1];
        short8 v;
        v[0]=f2bf(a0.x); v[1]=f2bf(a0.y); v[2]=f2bf(a0.z); v[3]=f2bf(a0.w);
        v[4]=f2bf(a1.x); v[5]=f2bf(a1.y); v[6]=f2bf(a1.z); v[7]=f2bf(a1.w);
        *reinterpret_cast<short8*>(wnyqG + j * 8) = v;
    }
}

// ---- main: 512 thr, 8 waves (2 freq x 4 frame), 128f x 256t; counted-vmcnt
// triple-buffered A pipeline (depth 2), raw barriers, setprio MFMA cluster ----
__global__ __launch_bounds__(512, 2)
void stft_mfma_kernel(const float* __restrict__ x,
                      const short* __restrict__ abL,
                      const short* __restrict__ wnyqG,
                      float* __restrict__ out)
{
    __shared__ __align__(16) char smem[XW_B + 3 * ASTEP + WNYQ_B];  // 120624 B
    char* const xw   = smem;
    char* const aBuf = smem + XW_B;
    char* const wnyq = smem + XW_B + 3 * ASTEP;

    const int tid  = threadIdx.x;
    const int wave = tid >> 6;
    const int lane = tid & 63;
    const int wr   = wave >> 2;          // 0..1 : freq half (64 rows)
    const int wc   = wave & 3;           // 0..3 : frame quarter (64 frames)
    const int lgrp = lane >> 4;
    const int l15  = lane & 15;

    // bijective XCD chunk swizzle: 480 = 8 * 60
    const int logical = (blockIdx.x & 7) * 60 + (blockIdx.x >> 3);
    const int ft = logical % NFT;
    const int b  = logical / NFT;
    const int t0 = ft * BN;

    const char* abLc = (const char*)abL;

    // ---- prologue: fp32 x window -> bf16 LDS (padded rows, reflect edges) ----
    {
        const float* __restrict__ xb = x + (size_t)b * NS;
        const int sbase = t0 * 128 - 256;
        #pragma unroll
        for (int i = 0; i < 9; ++i) {
            int g = tid + i * 512;
            if (g < XGROUPS) {
                int ix = sbase + g * 8;
                short8 v;
                if (ix >= 0 && ix + 8 <= NS) {
                    const float4* p = reinterpret_cast<const float4*>(xb + ix);
                    float4 a0 = p[0], a1 = p[1];
                    v[0]=f2bf(a0.x); v[1]=f2bf(a0.y); v[2]=f2bf(a0.z); v[3]=f2bf(a0.w);
                    v[4]=f2bf(a1.x); v[5]=f2bf(a1.y); v[6]=f2bf(a1.z); v[7]=f2bf(a1.w);
                } else {
                    #pragma unroll
                    for (int q = 0; q < 8; ++q) {
                        int idx = ix + q;
                        if (idx < 0) idx = -idx;
                        if (idx >= NS + 256) { v[q] = 0; continue; }
                        if (idx >= NS) idx = 2 * NS - 2 - idx;
                        v[q] = f2bf(xb[idx]);
                    }
                }
                *reinterpret_cast<short8*>(xw + (g >> 4) * XWPITCH + (g & 15) * 16) = v;
            }
        }
    }
    // nyq weights + stage(0), stage(1) issues; then full drain once
    if (wave == 0)
        gload_lds16((const char*)wnyqG + lane * 16, wnyq);
    #pragma unroll
    for (int st = 0; st < 2; ++st) {
        const char* sb = abLc + (size_t)st * ASTEP;
        char* dst = aBuf + st * ASTEP;
        int c = wave * 2;
        gload_lds16(sb + c * 1024 + lane * 16, dst + c * 1024);
        gload_lds16(sb + (c + 1) * 1024 + lane * 16, dst + (c + 1) * 1024);
    }
    __syncthreads();    // full drain (prologue only)

    f32x4 accR[4][4], accI[4][4];
    #pragma unroll
    for (int m = 0; m < 4; ++m)
        #pragma unroll
        for (int n = 0; n < 4; ++n) {
            accR[m][n] = f32x4{0.f,0.f,0.f,0.f};
            accI[m][n] = f32x4{0.f,0.f,0.f,0.f};
        }

    // A-read base: pl-plane + kslot region + row*16 (contiguous rows -> 0 conflicts)
    const int aBase = lgrp * 2048 + (wr * 64 + l15) * 16;

    #pragma unroll 1
    for (int s = 0; s < STEPS; ++s) {
        // counted wait: stage(s) landed; stage(s+1)'s 2 loads may stay in flight.
        // fp boundary (s=0,16): epilogue stores pollute the FIFO -> full drain.
        if ((s & 15) == 0) {
            asm volatile("s_waitcnt vmcnt(0)" ::: "memory");
        } else {
            asm volatile("s_waitcnt vmcnt(2)" ::: "memory");
        }
        asm volatile("s_waitcnt lgkmcnt(0)" ::: "memory");   // reads of s-1 consumed (cheap)
        __builtin_amdgcn_sched_barrier(0);
        __builtin_amdgcn_s_barrier();                        // raw barrier, no drain
        __builtin_amdgcn_sched_barrier(0);

        // ---- issue stage(s+2) into buffer (s+2)%3 (2-barrier write separation) ----
        if (s + 2 < STEPS) {
            const char* sb = abLc + (size_t)(s + 2) * ASTEP;
            char* dst = aBuf + ((s + 2) % 3) * ASTEP;
            int c = wave * 2;
            gload_lds16(sb + c * 1024 + lane * 16, dst + c * 1024);
            gload_lds16(sb + (c + 1) * 1024 + lane * 16, dst + (c + 1) * 1024);
        }
        __builtin_amdgcn_sched_barrier(0);

        // ---- compute(s) from buffer s%3 ----
        const char* aCur = aBuf + (s % 3) * ASTEP;
        const int ks32 = s & 15;
        short8 aRv[4], aIv[4], xv[4];
        #pragma unroll
        for (int m = 0; m < 4; ++m) {
            int off = aBase + m * 256;           // rows +16 per m -> +256B
            aRv[m] = *reinterpret_cast<const short8*>(aCur + off);
            aIv[m] = *reinterpret_cast<const short8*>(aCur + 8192 + off);
        }
        {
            int flat0 = (wc * 64 + l15) * 256 + ks32 * 64 + lgrp * 16;
            const char* xwl = xw + flat0 + ((flat0 >> 8) << 4);
            #pragma unroll
            for (int nt = 0; nt < 4; ++nt)
                xv[nt] = *reinterpret_cast<const short8*>(xwl + nt * (16 * XWPITCH));
        }
        __builtin_amdgcn_s_setprio(1);
        #pragma unroll
        for (int m = 0; m < 4; ++m)
            #pragma unroll
            for (int nt = 0; nt < 4; ++nt) {
                accR[m][nt] = __builtin_amdgcn_mfma_f32_16x16x32_bf16(aRv[m], xv[nt], accR[m][nt], 0, 0, 0);
                accI[m][nt] = __builtin_amdgcn_mfma_f32_16x16x32_bf16(aIv[m], xv[nt], accI[m][nt], 0, 0, 0);
            }
        __builtin_amdgcn_s_setprio(0);

        // ---- per-fp epilogue ----
        if ((s & 15) == 15) {
            const int fp = s >> 4;
            float* ob = out + (size_t)b * NFREQ * NFRAMES;
            const int fb = fp * 128 + wr * 64 + lgrp * 4;
            const int tb = t0 + wc * 64 + l15;
            #pragma unroll
            for (int m = 0; m < 4; ++m)
                #pragma unroll
                for (int nt = 0; nt < 4; ++nt) {
                    int t = tb + nt * 16;
                    if (t < NFRAMES) {
                        #pragma unroll
                        for (int r = 0; r < 4; ++r) {
                            int f = fb + m * 16 + r;
                            float vr = accR[m][nt][r], vi = accI[m][nt][r];
                            ob[(size_t)f * NFRAMES + t] = sqrtf(vr * vr + vi * vi);
                        }
                    }
                    accR[m][nt] = f32x4{0.f,0.f,0.f,0.f};
                    accI[m][nt] = f32x4{0.f,0.f,0.f,0.f};
                }
        }
    }

    // ---- Nyquist tail: f=256, |dot(x_frame, w)|; x & w in LDS ----
    {
        const int fl = wave * 32 + (lane & 31);       // local frame 0..255
        const int h  = lane >> 5;                     // window half
        const int xbase = (fl + 2 * h) * XWPITCH;
        const int wbase = h * 512;
        float acc = 0.f;
        #pragma unroll
        for (int j = 0; j < 32; ++j) {
            short8 xv8 = *reinterpret_cast<const short8*>(
                xw + xbase + (j >> 4) * XWPITCH + (j & 15) * 16);
            short8 wv8 = *reinterpret_cast<const short8*>(wnyq + wbase + j * 16);
            #pragma unroll
            for (int q = 0; q < 8; ++q)
                acc = fmaf(bf2f(xv8[q]), bf2f(wv8[q]), acc);
        }
        acc += __shfl_xor(acc, 32);
        int t = t0 + fl;
        if (h == 0 && t < NFRAMES)
            out[((size_t)b * NFREQ + 256) * NFRAMES + t] = fabsf(acc);
    }
}

extern "C" void kernel_launch(void* const* d_in, const int* in_sizes, int n_in,
                              void* d_out, int out_size, void* d_ws, size_t ws_size,
                              hipStream_t stream) {
    const float* x     = (const float*)d_in[0];
    const float* basis = (const float*)d_in[1];
    float* out = (float*)d_out;

    short* abL   = (short*)d_ws;                      // 32 steps x 16KB = 512KB
    short* wnyqG = abL + 262144;                      // 512 bf16

    prep_basis6<<<dim3(129), 256, 0, stream>>>(basis, abL, wnyqG);
    stft_mfma_kernel<<<dim3(NFT * NB), 512, 0, stream>>>(x, abL, wnyqG, out);  // 480 blocks
}

// Round 17
// 87.511 us; speedup vs baseline: 1.1555x; 1.1032x over previous
//
#include <hip/hip_runtime.h>

#define NFREQ   257
#define NFRAMES 3751
#define NS      480000
#define HOP     128
#define WIN     512

#define NB      32
#define BN      128                 // frames per block
#define NFT     30                  // 30*128 = 3840 frames
#define STEPS   32                  // 2 fp * 16 k32
#define XWPITCH 272                 // 128 samples (256B) + 16B pad
#define XW_B    35632               // 131 rows * 272
#define AHALF   16384               // one A step image: [2pl][64r][128B]
#define WNYQ_B  1024
#define XGROUPS 2096

typedef __attribute__((ext_vector_type(8))) short short8;
typedef __attribute__((ext_vector_type(4))) float f32x4;

__device__ __forceinline__ short f2bf(float f) {
    __bf16 b = (__bf16)f;
    return __builtin_bit_cast(short, b);
}
__device__ __forceinline__ float bf2f(short s) {
    unsigned int u = ((unsigned int)(unsigned short)s) << 16;
    return __builtin_bit_cast(float, u);
}
__device__ __forceinline__ void gload_lds16(const void* g, void* l) {
    __builtin_amdgcn_global_load_lds(
        (const __attribute__((address_space(1))) void*)g,
        (__attribute__((address_space(3))) void*)l, 16, 0, 0);
}

// ---- prep: bake 32-step A stream. Image byte ob (16B group g=ob/16):
// step=ob>>14, pl=(ob>>13)&1, r=(ob>>7)&63, s=(ob>>4)&7 ->
// u=s^(r&7), f=r+(u>>2)*64, kg=u&3; holds basis[pl, fp*128+f, ks32*32+kg*8 ..+8]
__global__ __launch_bounds__(256)
void prep_basis4(const float* __restrict__ basis,
                 short* __restrict__ abL, short* __restrict__ wnyqG) {
    int g = blockIdx.x * 256 + threadIdx.x;
    if (g < 32768) {
        int ob   = g * 16;
        int step = ob >> 14;                 // 0..31
        int rem  = ob & 16383;
        int pl   = rem >> 13;
        int r    = (rem >> 7) & 63;
        int s    = (rem >> 4) & 7;
        int u    = s ^ (r & 7);
        int f    = r + (u >> 2) * 64;        // 0..127
        int kg   = u & 3;
        int fp   = step >> 4;
        int ks32 = step & 15;
        int row  = pl * NFREQ + fp * 128 + f;   // < 2*257
        int k0   = ks32 * 32 + kg * 8;
        const float4* p = reinterpret_cast<const float4*>(
            basis + (size_t)row * WIN + k0);
        float4 a0 = p[0], a1 = p[1];
        short8 v;
        v[0]=f2bf(a0.x); v[1]=f2bf(a0.y); v[2]=f2bf(a0.z); v[3]=f2bf(a0.w);
        v[4]=f2bf(a1.x); v[5]=f2bf(a1.y); v[6]=f2bf(a1.z); v[7]=f2bf(a1.w);
        *reinterpret_cast<short8*>(reinterpret_cast<char*>(abL) + ob) = v;
    } else if (g < 32832) {                  // nyq row: real plane row 256
        int j = g - 32768;
        const float4* p = reinterpret_cast<const float4*>(basis + (size_t)256 * WIN + j * 8);
        float4 a0 = p[0], a1 = p[1];
        short8 v;
        v[0]=f2bf(a0.x); v[1]=f2bf(a0.y); v[2]=f2bf(a0.z); v[3]=f2bf(a0.w);
        v[4]=f2bf(a1.x); v[5]=f2bf(a1.y); v[6]=f2bf(a1.z); v[7]=f2bf(a1.w);
        *reinterpret_cast<short8*>(wnyqG + j * 8) = v;
    }
}

// ---- main: 4 waves stacked in freq (128f x 128t tile), wave 32f x 128t ----
__global__ __launch_bounds__(256, 2)
void stft_mfma_kernel(const float* __restrict__ x,
                      const short* __restrict__ abL,
                      const short* __restrict__ wnyqG,
                      float* __restrict__ out)
{
    __shared__ __align__(16) char smem[XW_B + 2 * AHALF + WNYQ_B];  // 69424 B
    char* const xw   = smem;
    char* const aBuf = smem + XW_B;
    char* const wnyq = smem + XW_B + 2 * AHALF;

    const int tid  = threadIdx.x;
    const int wave = tid >> 6;          // 0..3 : freq stack (32 rows each)
    const int lane = tid & 63;
    const int lgrp = lane >> 4;
    const int l15  = lane & 15;

    // bijective XCD chunk swizzle: 960 = 8 * 120
    const int logical = (blockIdx.x & 7) * 120 + (blockIdx.x >> 3);
    const int ft = logical % NFT;
    const int b  = logical / NFT;
    const int t0 = ft * BN;

    const char* abLc = (const char*)abL;

    // ---- prologue: issue step-0 A stage + nyq weights ----
    #pragma unroll
    for (int i = 0; i < 4; ++i) {
        int c = wave * 4 + i;                     // 0..15 KB-chunks
        gload_lds16(abLc + c * 1024 + lane * 16, aBuf + c * 1024);
    }
    if (wave == 0)
        gload_lds16((const char*)wnyqG + lane * 16, wnyq);

    // ---- prologue: fp32 x window -> bf16 LDS, padded rows, reflect edges ----
    {
        const float* __restrict__ xb = x + (size_t)b * NS;
        const int sbase = t0 * 128 - 256;
        #pragma unroll
        for (int i = 0; i < 9; ++i) {
            int g = tid + i * 256;
            if (g < XGROUPS) {
                int ix = sbase + g * 8;
                short8 v;
                if (ix >= 0 && ix + 8 <= NS) {
                    const float4* p = reinterpret_cast<const float4*>(xb + ix);
                    float4 a0 = p[0], a1 = p[1];
                    v[0]=f2bf(a0.x); v[1]=f2bf(a0.y); v[2]=f2bf(a0.z); v[3]=f2bf(a0.w);
                    v[4]=f2bf(a1.x); v[5]=f2bf(a1.y); v[6]=f2bf(a1.z); v[7]=f2bf(a1.w);
                } else {
                    #pragma unroll
                    for (int q = 0; q < 8; ++q) {
                        int idx = ix + q;
                        if (idx < 0) idx = -idx;
                        if (idx >= NS + 256) { v[q] = 0; continue; }
                        if (idx >= NS) idx = 2 * NS - 2 - idx;
                        v[q] = f2bf(xb[idx]);
                    }
                }
                *reinterpret_cast<short8*>(xw + (g >> 4) * XWPITCH + (g & 15) * 16) = v;
            }
        }
    }

    f32x4 accR[2][8], accI[2][8];
    #pragma unroll
    for (int m = 0; m < 2; ++m)
        #pragma unroll
        for (int n = 0; n < 8; ++n) {
            accR[m][n] = f32x4{0.f,0.f,0.f,0.f};
            accI[m][n] = f32x4{0.f,0.f,0.f,0.f};
        }

    // A-read addressing (2-way bank-free): r = (wave&1)*32 + m*16 + l15,
    // u = (wave>>1)*4 + lgrp, slot = u ^ (r&7); off = r*128 + slot*16
    const int rb = (wave & 1) * 32 + l15;
    const int ub = (wave >> 1) * 4 + lgrp;

    #pragma unroll 1
    for (int s = 0; s < STEPS; ++s) {
        // stage(s) loads + X writes visible to all after drain + barrier
        asm volatile("s_waitcnt vmcnt(0)" ::: "memory");
        __builtin_amdgcn_sched_barrier(0);
        __syncthreads();
        __builtin_amdgcn_sched_barrier(0);

        char* const aCur = aBuf + (s & 1) * AHALF;

        // ---- issue NEXT A stage into the other buffer (hidden under compute) ----
        if (s + 1 < STEPS) {
            char* const aNxt = aBuf + ((s + 1) & 1) * AHALF;
            const char* sb = abLc + (size_t)(s + 1) * AHALF;
            #pragma unroll
            for (int i = 0; i < 4; ++i) {
                int c = wave * 4 + i;
                gload_lds16(sb + c * 1024 + lane * 16, aNxt + c * 1024);
            }
        }
        __builtin_amdgcn_sched_barrier(0);   // pin: stage issue precedes compute

        // ---- compute this k32 ----
        const int ks32 = s & 15;
        short8 aRv[2], aIv[2], xv[8];
        #pragma unroll
        for (int m = 0; m < 2; ++m) {
            int r   = rb + m * 16;
            int off = r * 128 + ((ub ^ (r & 7)) << 4);
            aRv[m] = *reinterpret_cast<const short8*>(aCur + off);
            aIv[m] = *reinterpret_cast<const short8*>(aCur + 8192 + off);
        }
        {
            int r8 = ks32 * 64 + lgrp * 16;
            int T  = r8 + ((r8 >> 8) << 4);
            const char* xwl = xw + l15 * XWPITCH + T;
            #pragma unroll
            for (int nt = 0; nt < 8; ++nt)
                xv[nt] = *reinterpret_cast<const short8*>(xwl + nt * (16 * XWPITCH));
        }
        #pragma unroll
        for (int m = 0; m < 2; ++m)
            #pragma unroll
            for (int nt = 0; nt < 8; ++nt) {
                accR[m][nt] = __builtin_amdgcn_mfma_f32_16x16x32_bf16(aRv[m], xv[nt], accR[m][nt], 0, 0, 0);
                accI[m][nt] = __builtin_amdgcn_mfma_f32_16x16x32_bf16(aIv[m], xv[nt], accI[m][nt], 0, 0, 0);
            }

        // ---- per-fp epilogue (after 16 k32 steps) ----
        if ((s & 15) == 15) {
            const int fp = s >> 4;
            float* ob = out + (size_t)b * NFREQ * NFRAMES;
            const int fb = fp * 128 + wave * 32 + lgrp * 4;
            const int tb = t0 + l15;
            #pragma unroll
            for (int m = 0; m < 2; ++m)
                #pragma unroll
                for (int nt = 0; nt < 8; ++nt) {
                    int t = tb + nt * 16;
                    if (t < NFRAMES) {
                        #pragma unroll
                        for (int r = 0; r < 4; ++r) {
                            int f = fb + m * 16 + r;
                            float vr = accR[m][nt][r], vi = accI[m][nt][r];
                            ob[(size_t)f * NFRAMES + t] = sqrtf(vr * vr + vi * vi);
                        }
                    }
                    accR[m][nt] = f32x4{0.f,0.f,0.f,0.f};
                    accI[m][nt] = f32x4{0.f,0.f,0.f,0.f};
                }
        }
    }

    // ---- Nyquist tail: f=256, |dot(x_frame, w)|; x & w in LDS ----
    {
        const int fl = wave * 32 + (lane & 31);       // local frame 0..127
        const int h  = lane >> 5;                     // window half
        const int xbase = (fl + 2 * h) * XWPITCH;
        const int wbase = h * 512;
        float acc = 0.f;
        #pragma unroll
        for (int j = 0; j < 32; ++j) {
            short8 xv8 = *reinterpret_cast<const short8*>(
                xw + xbase + (j >> 4) * XWPITCH + (j & 15) * 16);
            short8 wv8 = *reinterpret_cast<const short8*>(wnyq + wbase + j * 16);
            #pragma unroll
            for (int q = 0; q < 8; ++q)
                acc = fmaf(bf2f(xv8[q]), bf2f(wv8[q]), acc);
        }
        acc += __shfl_xor(acc, 32);
        int t = t0 + fl;
        if (h == 0 && t < NFRAMES)
            out[((size_t)b * NFREQ + 256) * NFRAMES + t] = fabsf(acc);
    }
}

extern "C" void kernel_launch(void* const* d_in, const int* in_sizes, int n_in,
                              void* d_out, int out_size, void* d_ws, size_t ws_size,
                              hipStream_t stream) {
    const float* x     = (const float*)d_in[0];
    const float* basis = (const float*)d_in[1];
    float* out = (float*)d_out;

    short* abL   = (short*)d_ws;                      // 32 steps x 16KB = 512KB
    short* wnyqG = abL + 262144;                      // 512 bf16

    prep_basis4<<<dim3(129), 256, 0, stream>>>(basis, abL, wnyqG);
    stft_mfma_kernel<<<dim3(NFT * NB), 256, 0, stream>>>(x, abL, wnyqG, out);  // 960 blocks
}

// Round 18
// 80.986 us; speedup vs baseline: 1.2486x; 1.0806x over previous
//
#include <hip/hip_runtime.h>

#define NFREQ   257
#define NFRAMES 3751
#define NS      480000
#define HOP     128
#define WIN     512

#define NB      32
#define BN      128                 // frames per block
#define NFT     30                  // 30*128 = 3840 frames
#define STEPS   32                  // 2 fp * 16 k32
#define XWPITCH 272                 // 128 samples (256B) + 16B pad
#define XW_B    35632               // 131 rows * 272
#define AHALF   16384               // one A step image: [2pl][64r][128B]
#define WNYQ_B  2048                // 512 f32 weights
#define XGROUPS 2096

typedef __attribute__((ext_vector_type(8))) short short8;
typedef __attribute__((ext_vector_type(4))) float f32x4;

__device__ __forceinline__ short f2bf(float f) {
    __bf16 b = (__bf16)f;
    return __builtin_bit_cast(short, b);
}
__device__ __forceinline__ float bf2f(short s) {
    unsigned int u = ((unsigned int)(unsigned short)s) << 16;
    return __builtin_bit_cast(float, u);
}
__device__ __forceinline__ void gload_lds16(const void* g, void* l) {
    __builtin_amdgcn_global_load_lds(
        (const __attribute__((address_space(1))) void*)g,
        (__attribute__((address_space(3))) void*)l, 16, 0, 0);
}

// ---- prep: bake 32-step A stream. Image byte ob (16B group g=ob/16):
// step=ob>>14, pl=(ob>>13)&1, r=(ob>>7)&63, s=(ob>>4)&7 ->
// u=s^(r&7), f=r+(u>>2)*64, kg=u&3; holds basis[pl, fp*128+f, ks32*32+kg*8 ..+8]
__global__ __launch_bounds__(256)
void prep_basis4(const float* __restrict__ basis,
                 short* __restrict__ abL, short* __restrict__ wnyqG) {
    int g = blockIdx.x * 256 + threadIdx.x;
    if (g < 32768) {
        int ob   = g * 16;
        int step = ob >> 14;                 // 0..31
        int rem  = ob & 16383;
        int pl   = rem >> 13;
        int r    = (rem >> 7) & 63;
        int s    = (rem >> 4) & 7;
        int u    = s ^ (r & 7);
        int f    = r + (u >> 2) * 64;        // 0..127
        int kg   = u & 3;
        int fp   = step >> 4;
        int ks32 = step & 15;
        int row  = pl * NFREQ + fp * 128 + f;   // < 2*257
        int k0   = ks32 * 32 + kg * 8;
        const float4* p = reinterpret_cast<const float4*>(
            basis + (size_t)row * WIN + k0);
        float4 a0 = p[0], a1 = p[1];
        short8 v;
        v[0]=f2bf(a0.x); v[1]=f2bf(a0.y); v[2]=f2bf(a0.z); v[3]=f2bf(a0.w);
        v[4]=f2bf(a1.x); v[5]=f2bf(a1.y); v[6]=f2bf(a1.z); v[7]=f2bf(a1.w);
        *reinterpret_cast<short8*>(reinterpret_cast<char*>(abL) + ob) = v;
    } else if (g < 32832) {                  // nyq row: real plane row 256
        int j = g - 32768;
        const float4* p = reinterpret_cast<const float4*>(basis + (size_t)256 * WIN + j * 8);
        float4 a0 = p[0], a1 = p[1];
        short8 v;
        v[0]=f2bf(a0.x); v[1]=f2bf(a0.y); v[2]=f2bf(a0.z); v[3]=f2bf(a0.w);
        v[4]=f2bf(a1.x); v[5]=f2bf(a1.y); v[6]=f2bf(a1.z); v[7]=f2bf(a1.w);
        *reinterpret_cast<short8*>(wnyqG + j * 8) = v;
    }
}

// ---- main: 4 waves stacked in freq (128f x 128t tile), wave 32f x 128t;
// Nyquist dot-product interleaved 1 chunk/step into the MFMA shadow ----
__global__ __launch_bounds__(256, 2)
void stft_mfma_kernel(const float* __restrict__ x,
                      const short* __restrict__ abL,
                      const short* __restrict__ wnyqG,
                      float* __restrict__ out)
{
    __shared__ __align__(16) char smem[XW_B + 2 * AHALF + WNYQ_B];  // 70448 B
    char* const xw   = smem;
    char* const aBuf = smem + XW_B;
    float* const wny = reinterpret_cast<float*>(smem + XW_B + 2 * AHALF);

    const int tid  = threadIdx.x;
    const int wave = tid >> 6;          // 0..3 : freq stack (32 rows each)
    const int lane = tid & 63;
    const int lgrp = lane >> 4;
    const int l15  = lane & 15;

    // bijective XCD chunk swizzle: 960 = 8 * 120
    const int logical = (blockIdx.x & 7) * 120 + (blockIdx.x >> 3);
    const int ft = logical % NFT;
    const int b  = logical / NFT;
    const int t0 = ft * BN;

    const char* abLc = (const char*)abL;

    // ---- prologue: issue step-0 A stage ----
    #pragma unroll
    for (int i = 0; i < 4; ++i) {
        int c = wave * 4 + i;                     // 0..15 KB-chunks
        gload_lds16(abLc + c * 1024 + lane * 16, aBuf + c * 1024);
    }
    // nyq weights: bf16 global -> f32 LDS (512 values, 2/thread)
    {
        short a0 = wnyqG[tid * 2], a1 = wnyqG[tid * 2 + 1];
        wny[tid * 2]     = bf2f(a0);
        wny[tid * 2 + 1] = bf2f(a1);
    }

    // ---- prologue: fp32 x window -> bf16 LDS, padded rows, reflect edges ----
    {
        const float* __restrict__ xb = x + (size_t)b * NS;
        const int sbase = t0 * 128 - 256;
        #pragma unroll
        for (int i = 0; i < 9; ++i) {
            int g = tid + i * 256;
            if (g < XGROUPS) {
                int ix = sbase + g * 8;
                short8 v;
                if (ix >= 0 && ix + 8 <= NS) {
                    const float4* p = reinterpret_cast<const float4*>(xb + ix);
                    float4 a0 = p[0], a1 = p[1];
                    v[0]=f2bf(a0.x); v[1]=f2bf(a0.y); v[2]=f2bf(a0.z); v[3]=f2bf(a0.w);
                    v[4]=f2bf(a1.x); v[5]=f2bf(a1.y); v[6]=f2bf(a1.z); v[7]=f2bf(a1.w);
                } else {
                    #pragma unroll
                    for (int q = 0; q < 8; ++q) {
                        int idx = ix + q;
                        if (idx < 0) idx = -idx;
                        if (idx >= NS + 256) { v[q] = 0; continue; }
                        if (idx >= NS) idx = 2 * NS - 2 - idx;
                        v[q] = f2bf(xb[idx]);
                    }
                }
                *reinterpret_cast<short8*>(xw + (g >> 4) * XWPITCH + (g & 15) * 16) = v;
            }
        }
    }

    f32x4 accR[2][8], accI[2][8];
    #pragma unroll
    for (int m = 0; m < 2; ++m)
        #pragma unroll
        for (int n = 0; n < 8; ++n) {
            accR[m][n] = f32x4{0.f,0.f,0.f,0.f};
            accI[m][n] = f32x4{0.f,0.f,0.f,0.f};
        }

    // A-read addressing (2-way bank-free): r = (wave&1)*32 + m*16 + l15,
    // u = (wave>>1)*4 + lgrp, slot = u ^ (r&7); off = r*128 + slot*16
    const int rb = (wave & 1) * 32 + l15;
    const int ub = (wave >> 1) * 4 + lgrp;

    // nyquist assignment: frame fl (0..127), window half h; one 8-chunk per step
    const int nfl = wave * 32 + (lane & 31);
    const int nh  = lane >> 5;
    const int nyqXbase = (nfl + 2 * nh) * XWPITCH;
    const float* const nyqW = wny + nh * 256;
    float nacc = 0.f;

    #pragma unroll 1
    for (int s = 0; s < STEPS; ++s) {
        // stage(s) loads + X writes visible to all after drain + barrier
        asm volatile("s_waitcnt vmcnt(0)" ::: "memory");
        __builtin_amdgcn_sched_barrier(0);
        __syncthreads();
        __builtin_amdgcn_sched_barrier(0);

        char* const aCur = aBuf + (s & 1) * AHALF;

        // ---- issue NEXT A stage into the other buffer (hidden under compute) ----
        if (s + 1 < STEPS) {
            char* const aNxt = aBuf + ((s + 1) & 1) * AHALF;
            const char* sb = abLc + (size_t)(s + 1) * AHALF;
            #pragma unroll
            for (int i = 0; i < 4; ++i) {
                int c = wave * 4 + i;
                gload_lds16(sb + c * 1024 + lane * 16, aNxt + c * 1024);
            }
        }
        __builtin_amdgcn_sched_barrier(0);   // pin: stage issue precedes compute

        // ---- compute this k32 ----
        const int ks32 = s & 15;
        short8 aRv[2], aIv[2], xv[8];
        #pragma unroll
        for (int m = 0; m < 2; ++m) {
            int r   = rb + m * 16;
            int off = r * 128 + ((ub ^ (r & 7)) << 4);
            aRv[m] = *reinterpret_cast<const short8*>(aCur + off);
            aIv[m] = *reinterpret_cast<const short8*>(aCur + 8192 + off);
        }
        {
            int r8 = ks32 * 64 + lgrp * 16;
            int T  = r8 + ((r8 >> 8) << 4);
            const char* xwl = xw + l15 * XWPITCH + T;
            #pragma unroll
            for (int nt = 0; nt < 8; ++nt)
                xv[nt] = *reinterpret_cast<const short8*>(xwl + nt * (16 * XWPITCH));
        }
        #pragma unroll
        for (int m = 0; m < 2; ++m)
            #pragma unroll
            for (int nt = 0; nt < 8; ++nt) {
                accR[m][nt] = __builtin_amdgcn_mfma_f32_16x16x32_bf16(aRv[m], xv[nt], accR[m][nt], 0, 0, 0);
                accI[m][nt] = __builtin_amdgcn_mfma_f32_16x16x32_bf16(aIv[m], xv[nt], accI[m][nt], 0, 0, 0);
            }

        // ---- one 8-sample nyquist chunk (fills the MFMA shadow) ----
        {
            short8 nx = *reinterpret_cast<const short8*>(
                xw + nyqXbase + (s >> 4) * XWPITCH + (s & 15) * 16);
            const float* wrow = nyqW + s * 8;
            #pragma unroll
            for (int q = 0; q < 8; ++q)
                nacc = fmaf(bf2f(nx[q]), wrow[q], nacc);
        }

        // ---- per-fp epilogue (after 16 k32 steps) ----
        if ((s & 15) == 15) {
            const int fp = s >> 4;
            float* ob = out + (size_t)b * NFREQ * NFRAMES;
            const int fb = fp * 128 + wave * 32 + lgrp * 4;
            const int tb = t0 + l15;
            #pragma unroll
            for (int m = 0; m < 2; ++m)
                #pragma unroll
                for (int nt = 0; nt < 8; ++nt) {
                    int t = tb + nt * 16;
                    if (t < NFRAMES) {
                        #pragma unroll
                        for (int r = 0; r < 4; ++r) {
                            int f = fb + m * 16 + r;
                            float vr = accR[m][nt][r], vi = accI[m][nt][r];
                            ob[(size_t)f * NFRAMES + t] =
                                __builtin_amdgcn_sqrtf(vr * vr + vi * vi);
                        }
                    }
                    accR[m][nt] = f32x4{0.f,0.f,0.f,0.f};
                    accI[m][nt] = f32x4{0.f,0.f,0.f,0.f};
                }
        }
    }

    // ---- nyquist reduce + store (f=256) ----
    {
        nacc += __shfl_xor(nacc, 32);
        int t = t0 + nfl;
        if (nh == 0 && t < NFRAMES)
            out[((size_t)b * NFREQ + 256) * NFRAMES + t] = fabsf(nacc);
    }
}

extern "C" void kernel_launch(void* const* d_in, const int* in_sizes, int n_in,
                              void* d_out, int out_size, void* d_ws, size_t ws_size,
                              hipStream_t stream) {
    const float* x     = (const float*)d_in[0];
    const float* basis = (const float*)d_in[1];
    float* out = (float*)d_out;

    short* abL   = (short*)d_ws;                      // 32 steps x 16KB = 512KB
    short* wnyqG = abL + 262144;                      // 512 bf16

    prep_basis4<<<dim3(129), 256, 0, stream>>>(basis, abL, wnyqG);
    stft_mfma_kernel<<<dim3(NFT * NB), 256, 0, stream>>>(x, abL, wnyqG, out);  // 960 blocks
}

// Round 19
// 77.727 us; speedup vs baseline: 1.3010x; 1.0419x over previous
//
#include <hip/hip_runtime.h>

#define NFREQ   257
#define NFRAMES 3751
#define NS      480000
#define HOP     128
#define WIN     512

#define NB      32
#define BN      128                 // frames per block
#define NFT     30                  // 30*128 = 3840 frames
#define STEPS   32                  // 2 fp * 16 k32
#define XWPITCH 272                 // 128 samples (256B) + 16B pad
#define XW_B    35632               // 131 rows * 272
#define AHALF   16384               // one A step image: [4 wave][2pl][2m][64 perm x 16B]
#define WNYQ_B  2048                // 512 f32 weights
#define XGROUPS 2096

typedef __attribute__((ext_vector_type(8))) short short8;
typedef __attribute__((ext_vector_type(4))) float f32x4;

__device__ __forceinline__ short f2bf(float f) {
    __bf16 b = (__bf16)f;
    return __builtin_bit_cast(short, b);
}
__device__ __forceinline__ float bf2f(short s) {
    unsigned int u = ((unsigned int)(unsigned short)s) << 16;
    return __builtin_bit_cast(float, u);
}
__device__ __forceinline__ void gload_lds16(const void* g, void* l) {
    __builtin_amdgcn_global_load_lds(
        (const __attribute__((address_space(1))) void*)g,
        (__attribute__((address_space(3))) void*)l, 16, 0, 0);
}

// ---- prep: bake 32-step A stream, WAVE-PRIVATE regions.
// byte ob: step=ob>>14, w=(ob>>12)&3, pl=(ob>>11)&1, m=(ob>>10)&1,
// perm=(ob>>4)&63 -> l15=perm>>2, lgrp=perm&3.
// content: basis[pl, (step>>4)*128 + w*32 + m*16 + l15, (step&15)*32 + lgrp*8 ..+8]
// Wave w stages bytes [w*4096, (w+1)*4096) and reads ONLY those -> no barrier.
__global__ __launch_bounds__(256)
void prep_basis7(const float* __restrict__ basis,
                 short* __restrict__ abL, short* __restrict__ wnyqG) {
    int g = blockIdx.x * 256 + threadIdx.x;
    if (g < 32768) {
        int ob   = g * 16;
        int step = ob >> 14;                 // 0..31
        int w    = (ob >> 12) & 3;
        int pl   = (ob >> 11) & 1;
        int m    = (ob >> 10) & 1;
        int perm = (ob >> 4) & 63;
        int l15  = perm >> 2;
        int lgrp = perm & 3;
        int fr   = (step >> 4) * 128 + w * 32 + m * 16 + l15;   // 0..255 < 257
        int k0   = (step & 15) * 32 + lgrp * 8;
        const float4* p = reinterpret_cast<const float4*>(
            basis + ((size_t)(pl * NFREQ + fr)) * WIN + k0);
        float4 a0 = p[0], a1 = p[1];
        short8 v;
        v[0]=f2bf(a0.x); v[1]=f2bf(a0.y); v[2]=f2bf(a0.z); v[3]=f2bf(a0.w);
        v[4]=f2bf(a1.x); v[5]=f2bf(a1.y); v[6]=f2bf(a1.z); v[7]=f2bf(a1.w);
        *reinterpret_cast<short8*>(reinterpret_cast<char*>(abL) + ob) = v;
    } else if (g < 32832) {                  // nyq row: real plane row 256
        int j = g - 32768;
        const float4* p = reinterpret_cast<const float4*>(basis + (size_t)256 * WIN + j * 8);
        float4 a0 = p[0], a1 = p[1];
        short8 v;
        v[0]=f2bf(a0.x); v[1]=f2bf(a0.y); v[2]=f2bf(a0.z); v[3]=f2bf(a0.w);
        v[4]=f2bf(a1.x); v[5]=f2bf(a1.y); v[6]=f2bf(a1.z); v[7]=f2bf(a1.w);
        *reinterpret_cast<short8*>(wnyqG + j * 8) = v;
    }
}

// ---- main: 128f x 128t tile, wave 32f x 128t; BARRIER-FREE K-loop
// (wave-private A staging, per-wave vmcnt only); nyq interleaved ----
__global__ __launch_bounds__(256, 2)
void stft_mfma_kernel(const float* __restrict__ x,
                      const short* __restrict__ abL,
                      const short* __restrict__ wnyqG,
                      float* __restrict__ out)
{
    __shared__ __align__(16) char smem[XW_B + 2 * AHALF + WNYQ_B];  // 70448 B
    char* const xw   = smem;
    char* const aBuf = smem + XW_B;
    float* const wny = reinterpret_cast<float*>(smem + XW_B + 2 * AHALF);

    const int tid  = threadIdx.x;
    const int wave = tid >> 6;          // 0..3 : freq stack (32 rows each)
    const int lane = tid & 63;
    const int lgrp = lane >> 4;
    const int l15  = lane & 15;

    // bijective XCD chunk swizzle: 960 = 8 * 120
    const int logical = (blockIdx.x & 7) * 120 + (blockIdx.x >> 3);
    const int ft = logical % NFT;
    const int b  = logical / NFT;
    const int t0 = ft * BN;

    const char* abLc = (const char*)abL;
    const int wBase = wave * 4096;

    // ---- prologue: issue step-0 A stage (own region) ----
    #pragma unroll
    for (int i = 0; i < 4; ++i)
        gload_lds16(abLc + wBase + i * 1024 + lane * 16,
                    aBuf + wBase + i * 1024);
    // nyq weights: bf16 global -> f32 LDS (512 values, 2/thread)
    {
        short a0 = wnyqG[tid * 2], a1 = wnyqG[tid * 2 + 1];
        wny[tid * 2]     = bf2f(a0);
        wny[tid * 2 + 1] = bf2f(a1);
    }

    // ---- prologue: fp32 x window -> bf16 LDS, padded rows, reflect edges ----
    {
        const float* __restrict__ xb = x + (size_t)b * NS;
        const int sbase = t0 * 128 - 256;
        #pragma unroll
        for (int i = 0; i < 9; ++i) {
            int g = tid + i * 256;
            if (g < XGROUPS) {
                int ix = sbase + g * 8;
                short8 v;
                if (ix >= 0 && ix + 8 <= NS) {
                    const float4* p = reinterpret_cast<const float4*>(xb + ix);
                    float4 a0 = p[0], a1 = p[1];
                    v[0]=f2bf(a0.x); v[1]=f2bf(a0.y); v[2]=f2bf(a0.z); v[3]=f2bf(a0.w);
                    v[4]=f2bf(a1.x); v[5]=f2bf(a1.y); v[6]=f2bf(a1.z); v[7]=f2bf(a1.w);
                } else {
                    #pragma unroll
                    for (int q = 0; q < 8; ++q) {
                        int idx = ix + q;
                        if (idx < 0) idx = -idx;
                        if (idx >= NS + 256) { v[q] = 0; continue; }
                        if (idx >= NS) idx = 2 * NS - 2 - idx;
                        v[q] = f2bf(xb[idx]);
                    }
                }
                *reinterpret_cast<short8*>(xw + (g >> 4) * XWPITCH + (g & 15) * 16) = v;
            }
        }
    }
    __syncthreads();    // the ONLY barrier: X window visibility

    f32x4 accR[2][8], accI[2][8];
    #pragma unroll
    for (int m = 0; m < 2; ++m)
        #pragma unroll
        for (int n = 0; n < 8; ++n) {
            accR[m][n] = f32x4{0.f,0.f,0.f,0.f};
            accI[m][n] = f32x4{0.f,0.f,0.f,0.f};
        }

    const int aPerm = (l15 * 4 + lgrp) * 16;   // lane-linear fragment slot

    // nyquist assignment: frame fl (0..127), window half h; one 8-chunk per step
    const int nfl = wave * 32 + (lane & 31);
    const int nh  = lane >> 5;
    const int nyqXbase = (nfl + 2 * nh) * XWPITCH;
    const float* const nyqW = wny + nh * 256;
    float nacc = 0.f;

    #pragma unroll 1
    for (int s = 0; s < STEPS; ++s) {
        // wait for OWN stage(s) loads only (per-wave vmcnt) — no block barrier
        asm volatile("s_waitcnt vmcnt(0)" ::: "memory");
        __builtin_amdgcn_sched_barrier(0);

        // ---- issue stage(s+1) into the other buffer (own region) ----
        if (s + 1 < STEPS) {
            const char* sb = abLc + (size_t)(s + 1) * AHALF + wBase;
            char* dst = aBuf + ((s + 1) & 1) * AHALF + wBase;
            #pragma unroll
            for (int i = 0; i < 4; ++i)
                gload_lds16(sb + i * 1024 + lane * 16, dst + i * 1024);
        }
        __builtin_amdgcn_sched_barrier(0);   // pin: stage issue precedes compute

        // ---- compute this k32 from own region of buf[s&1] ----
        const int ks32 = s & 15;
        const char* aCur = aBuf + (s & 1) * AHALF + wBase;
        short8 aRv[2], aIv[2], xv[8];
        #pragma unroll
        for (int m = 0; m < 2; ++m) {
            aRv[m] = *reinterpret_cast<const short8*>(aCur + m * 1024 + aPerm);
            aIv[m] = *reinterpret_cast<const short8*>(aCur + 2048 + m * 1024 + aPerm);
        }
        {
            int r8 = ks32 * 64 + lgrp * 16;
            int T  = r8 + ((r8 >> 8) << 4);
            const char* xwl = xw + l15 * XWPITCH + T;
            #pragma unroll
            for (int nt = 0; nt < 8; ++nt)
                xv[nt] = *reinterpret_cast<const short8*>(xwl + nt * (16 * XWPITCH));
        }
        #pragma unroll
        for (int m = 0; m < 2; ++m)
            #pragma unroll
            for (int nt = 0; nt < 8; ++nt) {
                accR[m][nt] = __builtin_amdgcn_mfma_f32_16x16x32_bf16(aRv[m], xv[nt], accR[m][nt], 0, 0, 0);
                accI[m][nt] = __builtin_amdgcn_mfma_f32_16x16x32_bf16(aIv[m], xv[nt], accI[m][nt], 0, 0, 0);
            }

        // ---- one 8-sample nyquist chunk (fills the MFMA shadow) ----
        {
            short8 nx = *reinterpret_cast<const short8*>(
                xw + nyqXbase + (s >> 4) * XWPITCH + (s & 15) * 16);
            const float* wrow = nyqW + s * 8;
            #pragma unroll
            for (int q = 0; q < 8; ++q)
                nacc = fmaf(bf2f(nx[q]), wrow[q], nacc);
        }

        // ---- per-fp epilogue (after 16 k32 steps) ----
        if ((s & 15) == 15) {
            const int fp = s >> 4;
            float* ob = out + (size_t)b * NFREQ * NFRAMES;
            const int fb = fp * 128 + wave * 32 + lgrp * 4;
            const int tb = t0 + l15;
            #pragma unroll
            for (int m = 0; m < 2; ++m)
                #pragma unroll
                for (int nt = 0; nt < 8; ++nt) {
                    int t = tb + nt * 16;
                    if (t < NFRAMES) {
                        #pragma unroll
                        for (int r = 0; r < 4; ++r) {
                            int f = fb + m * 16 + r;
                            float vr = accR[m][nt][r], vi = accI[m][nt][r];
                            ob[(size_t)f * NFRAMES + t] =
                                __builtin_amdgcn_sqrtf(vr * vr + vi * vi);
                        }
                    }
                    accR[m][nt] = f32x4{0.f,0.f,0.f,0.f};
                    accI[m][nt] = f32x4{0.f,0.f,0.f,0.f};
                }
        }
    }

    // ---- nyquist reduce + store (f=256) ----
    {
        nacc += __shfl_xor(nacc, 32);
        int t = t0 + nfl;
        if (nh == 0 && t < NFRAMES)
            out[((size_t)b * NFREQ + 256) * NFRAMES + t] = fabsf(nacc);
    }
}

extern "C" void kernel_launch(void* const* d_in, const int* in_sizes, int n_in,
                              void* d_out, int out_size, void* d_ws, size_t ws_size,
                              hipStream_t stream) {
    const float* x     = (const float*)d_in[0];
    const float* basis = (const float*)d_in[1];
    float* out = (float*)d_out;

    short* abL   = (short*)d_ws;                      // 32 steps x 16KB = 512KB
    short* wnyqG = abL + 262144;                      // 512 bf16

    prep_basis7<<<dim3(129), 256, 0, stream>>>(basis, abL, wnyqG);
    stft_mfma_kernel<<<dim3(NFT * NB), 256, 0, stream>>>(x, abL, wnyqG, out);  // 960 blocks
}